// Round 7
// baseline (1197.255 us; speedup 1.0000x reference)
//
#include <hip/hip_runtime.h>
#include <math.h>

#define NB 256
#define NT 1024
#define ND 32
#define NH 64
#define NL 32
#define DT0 0.4f
#define XB 36    // staged x row: [y0..y31, ts, pad3]
#define BT 512   // 8 waves

__device__ __forceinline__ float dot4(float4 a, float4 b) {
    return a.x * b.x + a.y * b.y + a.z * b.z + a.w * b.w;
}
__device__ __forceinline__ float fsigm(float x) {
    return __fdividef(1.0f, 1.0f + __expf(-x));
}
__device__ __forceinline__ float ftanh(float x) {
    float cx = fminf(fmaxf(x, -15.0f), 15.0f);
    float e2 = __expf(2.0f * cx);
    return __fdividef(e2 - 1.0f, e2 + 1.0f);
}
__device__ __forceinline__ float fsoftplus(float x) {
    return fmaxf(x, 0.0f) + __logf(1.0f + __expf(-fabsf(x)));
}

// DPP cross-lane adds on the VALU pipe.
// 0xB1 = quad_perm xor1 ; 0x4E = quad_perm xor2 ; 0x104 = row_shl:4
// (lane i <- lane i+4, 0-filled at row edge with bound_ctrl): completes an
// 8-lane group sum at lanes with (lane&7)==0.
template <int CTRL>
__device__ __forceinline__ float dpp_add(float x) {
    int t = __builtin_amdgcn_update_dpp(0, __float_as_int(x), CTRL, 0xF, 0xF, true);
    return x + __int_as_float(t);
}
__device__ __forceinline__ float quad_reduce(float x) {
    x = dpp_add<0xB1>(x);
    x = dpp_add<0x4E>(x);
    return x;
}
__device__ __forceinline__ float red8(float x) {   // total valid at (lane&7)==0
    x = dpp_add<0xB1>(x);
    x = dpp_add<0x4E>(x);
    x = dpp_add<0x104>(x);
    return x;
}

extern "C" __global__ void __launch_bounds__(BT, 1)
latentode_fused(const float* __restrict__ ts,      // (B,T)
                const float* __restrict__ ys,      // (B,T,D)
                const float* __restrict__ eps,     // (B,L)
                const float* __restrict__ scale_p, // ()
                const float* __restrict__ fw0, const float* __restrict__ fb0,
                const float* __restrict__ fw1, const float* __restrict__ fb1,
                const float* __restrict__ fw2, const float* __restrict__ fb2,
                const float* __restrict__ gwi, const float* __restrict__ gwh,
                const float* __restrict__ gb,  const float* __restrict__ gbn,
                const float* __restrict__ hlw, const float* __restrict__ hlb,
                const float* __restrict__ lw0, const float* __restrict__ lb0,
                const float* __restrict__ lw1, const float* __restrict__ lb1,
                const float* __restrict__ lw2, const float* __restrict__ lb2,
                const float* __restrict__ hdw, const float* __restrict__ hdb,
                float* __restrict__ out)
{
    const int b   = blockIdx.x;
    const int tid = threadIdx.x;
    const int w   = tid >> 6;
    const int ln  = tid & 63;

    __shared__ __align__(16) float xb[NT * XB];    // 147456 B staged input
    __shared__ __align__(16) float hbuf[2][64];    // GRU h, double-buffered
    __shared__ __align__(16) float a0b[64];
    __shared__ __align__(16) float a1b[64];
    __shared__ __align__(16) float tmpb[64];
    __shared__ __align__(16) float ybuf[64];
    __shared__ __align__(16) float latb[32];
    __shared__ float redr[8];

    // ---------------- stage ts/ys into LDS (one-time) -------------------------
    for (int i = tid; i < NT * 8; i += BT) {
        const int row = i >> 3, q = i & 7;
        *(float4*)&xb[row * XB + q * 4] =
            *(const float4*)(ys + (size_t)(b * NT + row) * ND + q * 4);
    }
    for (int i = tid; i < NT; i += BT) xb[i * XB + 32] = ts[b * NT + i];

    // ---------------- GRU weights: unit u = tid>>3, k-part p = tid&7 ----------
    const int u = tid >> 3;          // 0..63
    const int p = tid & 7;           // 0..7
    // Wh rows u, 64+u, 128+u : k-slice [8p..8p+7] (16B-aligned)
    const float4* whr = (const float4*)(gwh + (u)       * 64 + p * 8);
    const float4* whz = (const float4*)(gwh + (64 + u)  * 64 + p * 8);
    const float4* whn = (const float4*)(gwh + (128 + u) * 64 + p * 8);
    const float4 WR0=whr[0], WR1=whr[1];
    const float4 WZ0=whz[0], WZ1=whz[1];
    const float4 WN0=whn[0], WN1=whn[1];
    // Wi rows (33 wide): y-slice [4p..4p+3], ts weight only at p==0
    const float* gr = gwi + u * 33;
    const float* gz = gwi + (64 + u) * 33;
    const float* gn = gwi + (128 + u) * 33;
    const int o = 4 * p;
    const float4 RIA = make_float4(gr[1+o], gr[2+o], gr[3+o], gr[4+o]);
    const float4 ZIA = make_float4(gz[1+o], gz[2+o], gz[3+o], gz[4+o]);
    const float4 NIA = make_float4(gn[1+o], gn[2+o], gn[3+o], gn[4+o]);
    const float RT  = (p == 0) ? gr[0] : 0.0f;
    const float ZT  = (p == 0) ? gz[0] : 0.0f;
    const float NTW = (p == 0) ? gn[0] : 0.0f;
    const float gbr_ = gb[u], gbz_ = gb[64 + u], gbn_ = gb[128 + u];
    const float bnv  = gbn[u];

    if (tid < 64) hbuf[0][tid] = 0.0f;
    __syncthreads();

    // ---------------- GRU scan: 1 barrier/step, 8-way k-split ------------------
    float hreg = 0.0f;
    float4 xA = *(const float4*)(&xb[0] + o);
    float tsv = xb[32];
    for (int s = 0; s < NT; ++s) {
        const int sn = (s + 1 < NT) ? (s + 1) : s;
        const float4 nxA = *(const float4*)(&xb[sn * XB] + o);
        const float ntsv = xb[sn * XB + 32];

        const float4* hv = (const float4*)&hbuf[s & 1][p * 8];
        const float4 h0 = hv[0], h1 = hv[1];

        float ar  = dot4(WR0,h0) + dot4(WR1,h1) + dot4(RIA,xA) + RT * tsv;
        float az  = dot4(WZ0,h0) + dot4(WZ1,h1) + dot4(ZIA,xA) + ZT * tsv;
        float ahn = dot4(WN0,h0) + dot4(WN1,h1);
        float ain = dot4(NIA,xA) + NTW * tsv;

        ar  = red8(ar);
        az  = red8(az);
        ahn = red8(ahn);
        ain = red8(ain);

        if (p == 0) {
            const float rg = fsigm(ar + gbr_);
            const float zg = fsigm(az + gbz_);
            const float ng = ftanh(ain + gbn_ + rg * (ahn + bnv));
            hreg = ng + zg * (hreg - ng);
            hbuf[(s + 1) & 1][u] = hreg;
        }
        xA = nxA; tsv = ntsv;
        __syncthreads();
    }
    // final h in hbuf[0] (NT even)

    // ---------------- context -> latent -> y0 (one-time) ----------------------
    if (tid < 64) {
        const float4* wp = (const float4*)(hlw + tid * 64);
        const float4* hv = (const float4*)&hbuf[0][0];
        float a0 = hlb[tid], a1 = 0.0f;
#pragma unroll
        for (int q = 0; q < 16; q += 2) { a0 += dot4(wp[q], hv[q]); a1 += dot4(wp[q+1], hv[q+1]); }
        tmpb[tid] = a0 + a1;
    }
    __syncthreads();
    float klpart = 0.0f;
    if (tid < 32) {
        const float mean   = tmpb[tid];
        const float logstd = tmpb[32 + tid];
        const float stdv   = __expf(logstd);
        latb[tid] = mean + eps[b * NL + tid] * stdv;
        klpart = 0.5f * (mean * mean + stdv * stdv - 2.0f * logstd - 1.0f);
    }
    __syncthreads();
    if (tid < 64) {
        const float4* wp = (const float4*)(lw0 + tid * 32);
        const float4* lv = (const float4*)latb;
        float a0 = lb0[tid], a1 = 0.0f;
#pragma unroll
        for (int q = 0; q < 8; q += 2) { a0 += dot4(wp[q], lv[q]); a1 += dot4(wp[q+1], lv[q+1]); }
        a0b[tid] = fmaxf(a0 + a1, 0.0f);
    }
    __syncthreads();
    if (tid < 64) {
        const float4* wp = (const float4*)(lw1 + tid * 64);
        const float4* av = (const float4*)a0b;
        float a0 = lb1[tid], a1 = 0.0f;
#pragma unroll
        for (int q = 0; q < 16; q += 2) { a0 += dot4(wp[q], av[q]); a1 += dot4(wp[q+1], av[q+1]); }
        a1b[tid] = fmaxf(a0 + a1, 0.0f);
    }
    __syncthreads();
    if (tid < 64) {
        const float4* wp = (const float4*)(lw2 + tid * 64);
        const float4* tv = (const float4*)a1b;
        float a0 = lb2[tid], a1 = 0.0f;
#pragma unroll
        for (int q = 0; q < 16; q += 2) { a0 += dot4(wp[q], tv[q]); a1 += dot4(wp[q+1], tv[q+1]); }
        ybuf[tid] = a0 + a1;   // y0
    }
    __syncthreads();

    // ---------------- Euler weights -------------------------------------------
    // waves 0-3 (tid<256): layers, er/ep 4-way split. waves 4-7: hd 8-way split.
    const int er = (tid < 256) ? (tid >> 2) : 0;
    const int ep = tid & 3;
    const float4* q0 = (const float4*)(fw0 + er * 64 + ep * 16);
    const float4 E00=q0[0], E01=q0[1], E02=q0[2], E03=q0[3];
    const float4* q1 = (const float4*)(fw1 + er * 64 + ep * 16);
    const float4 E10=q1[0], E11=q1[1], E12=q1[2], E13=q1[3];
    const float4* q2 = (const float4*)(fw2 + er * 64 + ep * 16);
    const float4 E20=q2[0], E21=q2[1], E22=q2[2], E23=q2[3];
    const float b0 = fb0[er], b1 = fb1[er], b2 = fb2[er];
    const int hu = (tid >= 256) ? ((tid - 256) >> 3) : 0;   // 0..31
    const int hp = tid & 7;
    const float4* qh = (const float4*)(hdw + hu * 64 + hp * 8);
    const float4 HD0 = qh[0], HD1 = qh[1];
    const float hdbias = hdb[hu];
    const float dts = DT0 * scale_p[0];
    float ylocal = (tid < 256 && ep == 0) ? ybuf[er] : 0.0f;
    float rec = 0.0f;

    // ---------------- Euler scan: 3 phases; hd on waves 4-7 in P1 -------------
    for (int s = 0; s < NT; ++s) {
        // P1: layer0 (waves 0-3) | hd projection + recon (waves 4-7)
        if (tid < 256) {
            const float4* yv = (const float4*)ybuf;
            float l0 = dot4(E00, yv[ep*4+0]) + dot4(E01, yv[ep*4+1])
                     + dot4(E02, yv[ep*4+2]) + dot4(E03, yv[ep*4+3]);
            l0 = quad_reduce(l0);
            if (ep == 0) a0b[er] = fsoftplus(l0 + b0);
        } else {
            const float4* yv = (const float4*)ybuf;
            float ph = dot4(HD0, yv[hp*2+0]) + dot4(HD1, yv[hp*2+1]);
            ph = red8(ph);
            if (hp == 0 && s > 0) {
                const float d = xb[(s - 1) * XB + hu] - (ph + hdbias);
                rec += d * d;
            }
        }
        __syncthreads();
        // P2: layer1 (waves 0-3)
        if (tid < 256) {
            const float4* av = (const float4*)a0b;
            float l1 = dot4(E10, av[ep*4+0]) + dot4(E11, av[ep*4+1])
                     + dot4(E12, av[ep*4+2]) + dot4(E13, av[ep*4+3]);
            l1 = quad_reduce(l1);
            if (ep == 0) a1b[er] = fsoftplus(l1 + b1);
        }
        __syncthreads();
        // P3: layer2 + y update (waves 0-3; lane (er,0) keeps y in register)
        if (tid < 256) {
            const float4* bv = (const float4*)a1b;
            float l2 = dot4(E20, bv[ep*4+0]) + dot4(E21, bv[ep*4+1])
                     + dot4(E22, bv[ep*4+2]) + dot4(E23, bv[ep*4+3]);
            l2 = quad_reduce(l2);
            if (ep == 0) {
                ylocal += dts * ftanh(l2 + b2);
                ybuf[er] = ylocal;
            }
        }
        __syncthreads();
    }

    // epilogue: hd of y_T vs ys[T-1] (waves 4-7)
    if (tid >= 256) {
        const float4* yv = (const float4*)ybuf;
        float ph = dot4(HD0, yv[hp*2+0]) + dot4(HD1, yv[hp*2+1]);
        ph = red8(ph);
        if (hp == 0) {
            const float d = xb[(NT - 1) * XB + hu] - (ph + hdbias);
            rec += d * d;
        }
    }
    // recon reduce within waves 4-7 (values live at (ln&7)==0 lanes)
    {
        float rv = rec;
        rv += __shfl_xor(rv, 8);
        rv += __shfl_xor(rv, 16);
        rv += __shfl_xor(rv, 32);
        if (tid >= 256 && ln == 0) redr[w - 4] = rv;
    }
    // KL reduce (lanes 0..31 of wave 0)
    float klv = klpart;
    klv += __shfl_xor(klv, 1);
    klv += __shfl_xor(klv, 2);
    klv += __shfl_xor(klv, 4);
    klv += __shfl_xor(klv, 8);
    klv += __shfl_xor(klv, 16);
    __syncthreads();
    if (tid == 0) {
        const float rs = redr[0] + redr[1] + redr[2] + redr[3];
        out[b] = 0.5f * rs + klv;
    }
}

extern "C" void kernel_launch(void* const* d_in, const int* in_sizes, int n_in,
                              void* d_out, int out_size, void* d_ws, size_t ws_size,
                              hipStream_t stream) {
    (void)in_sizes; (void)n_in; (void)out_size; (void)d_ws; (void)ws_size;
    const float* ts      = (const float*)d_in[0];
    const float* ys      = (const float*)d_in[1];
    const float* eps     = (const float*)d_in[2];
    const float* scale_p = (const float*)d_in[3];
    const float* fw0     = (const float*)d_in[4];
    const float* fb0     = (const float*)d_in[5];
    const float* fw1     = (const float*)d_in[6];
    const float* fb1     = (const float*)d_in[7];
    const float* fw2     = (const float*)d_in[8];
    const float* fb2     = (const float*)d_in[9];
    const float* gwi     = (const float*)d_in[10];
    const float* gwh     = (const float*)d_in[11];
    const float* gbv     = (const float*)d_in[12];
    const float* gbn     = (const float*)d_in[13];
    const float* hlw     = (const float*)d_in[14];
    const float* hlb     = (const float*)d_in[15];
    const float* lw0     = (const float*)d_in[16];
    const float* lb0     = (const float*)d_in[17];
    const float* lw1     = (const float*)d_in[18];
    const float* lb1     = (const float*)d_in[19];
    const float* lw2     = (const float*)d_in[20];
    const float* lb2     = (const float*)d_in[21];
    const float* hdw     = (const float*)d_in[22];
    const float* hdb     = (const float*)d_in[23];
    float* out = (float*)d_out;

    hipLaunchKernelGGL(latentode_fused, dim3(NB), dim3(BT), 0, stream,
                       ts, ys, eps, scale_p, fw0, fb0, fw1, fb1, fw2, fb2,
                       gwi, gwh, gbv, gbn, hlw, hlb, lw0, lb0, lw1, lb1,
                       lw2, lb2, hdw, hdb, out);
}

// Round 8
// 1116.856 us; speedup vs baseline: 1.0720x; 1.0720x over previous
//
#include <hip/hip_runtime.h>
#include <math.h>

#define NB 256
#define NT 1024
#define ND 32
#define NH 64
#define NL 32
#define DT0 0.4f
#define XB 36   // staged x row: [y0..y31, ts, pad3]

__device__ __forceinline__ float dot4(float4 a, float4 b) {
    return a.x * b.x + a.y * b.y + a.z * b.z + a.w * b.w;
}
__device__ __forceinline__ float fsigm(float x) {
    return __fdividef(1.0f, 1.0f + __expf(-x));
}
__device__ __forceinline__ float ftanh(float x) {
    float cx = fminf(fmaxf(x, -15.0f), 15.0f);
    float e2 = __expf(2.0f * cx);
    return __fdividef(e2 - 1.0f, e2 + 1.0f);
}
__device__ __forceinline__ float fsoftplus(float x) {
    return fmaxf(x, 0.0f) + __logf(1.0f + __expf(-fabsf(x)));
}

// DPP cross-lane adds on the VALU pipe (no LDS/bpermute latency).
// 0xB1 = quad_perm xor1 ; 0x4E = quad_perm xor2 ; 0x104 = row_shl:4
// (lane i <- lane i+4, 0-filled at row edge with bound_ctrl): completes an
// 8-lane group sum at lanes with (lane&7)==0.
template <int CTRL>
__device__ __forceinline__ float dpp_add(float x) {
    int t = __builtin_amdgcn_update_dpp(0, __float_as_int(x), CTRL, 0xF, 0xF, true);
    return x + __int_as_float(t);
}
__device__ __forceinline__ float quad_reduce(float x) {
    x = dpp_add<0xB1>(x);
    x = dpp_add<0x4E>(x);
    return x;
}
__device__ __forceinline__ float red8(float x) {   // total valid at (lane&7)==0
    x = dpp_add<0xB1>(x);
    x = dpp_add<0x4E>(x);
    x = dpp_add<0x104>(x);
    return x;
}

extern "C" __global__ void __launch_bounds__(256, 1)
latentode_fused(const float* __restrict__ ts,      // (B,T)
                const float* __restrict__ ys,      // (B,T,D)
                const float* __restrict__ eps,     // (B,L)
                const float* __restrict__ scale_p, // ()
                const float* __restrict__ fw0, const float* __restrict__ fb0,
                const float* __restrict__ fw1, const float* __restrict__ fb1,
                const float* __restrict__ fw2, const float* __restrict__ fb2,
                const float* __restrict__ gwi, const float* __restrict__ gwh,
                const float* __restrict__ gb,  const float* __restrict__ gbn,
                const float* __restrict__ hlw, const float* __restrict__ hlb,
                const float* __restrict__ lw0, const float* __restrict__ lb0,
                const float* __restrict__ lw1, const float* __restrict__ lb1,
                const float* __restrict__ lw2, const float* __restrict__ lb2,
                const float* __restrict__ hdw, const float* __restrict__ hdb,
                float* __restrict__ out)
{
    const int b   = blockIdx.x;
    const int tid = threadIdx.x;
    const int w   = tid >> 6;

    __shared__ __align__(16) float xb[(NT + 1) * XB];  // +1 pad row: clampless prefetch
    __shared__ __align__(16) float hbuf[2][64];        // GRU h, double-buffered
    __shared__ __align__(16) float a0b[64];
    __shared__ __align__(16) float a1b[64];
    __shared__ __align__(16) float tmpb[64];
    __shared__ __align__(16) float ybuf[64];
    __shared__ __align__(16) float latb[32];
    __shared__ float redr[32];

    // ---------------- stage ts/ys into LDS (one-time) -------------------------
    for (int i = tid; i < NT * 8; i += 256) {
        const int row = i >> 3, q = i & 7;
        *(float4*)&xb[row * XB + q * 4] =
            *(const float4*)(ys + (size_t)(b * NT + row) * ND + q * 4);
    }
    for (int i = tid; i < NT; i += 256) xb[i * XB + 32] = ts[b * NT + i];

    // ---------------- GRU weights: unit u = tid>>2, k-part p = tid&3 ----------
    const int u = tid >> 2;
    const int p = tid & 3;
    const float4* whr = (const float4*)(gwh + (u)       * 64 + p * 16);
    const float4* whz = (const float4*)(gwh + (64 + u)  * 64 + p * 16);
    const float4* whn = (const float4*)(gwh + (128 + u) * 64 + p * 16);
    const float4 WR0=whr[0], WR1=whr[1], WR2=whr[2], WR3=whr[3];
    const float4 WZ0=whz[0], WZ1=whz[1], WZ2=whz[2], WZ3=whz[3];
    const float4 WN0=whn[0], WN1=whn[1], WN2=whn[2], WN3=whn[3];
    const float* gr = gwi + u * 33;
    const float* gz = gwi + (64 + u) * 33;
    const float* gn = gwi + (128 + u) * 33;
    const int o = 8 * p;
    const float4 RIA = make_float4(gr[1+o], gr[2+o], gr[3+o], gr[4+o]);
    const float4 RIB = make_float4(gr[5+o], gr[6+o], gr[7+o], gr[8+o]);
    const float4 ZIA = make_float4(gz[1+o], gz[2+o], gz[3+o], gz[4+o]);
    const float4 ZIB = make_float4(gz[5+o], gz[6+o], gz[7+o], gz[8+o]);
    const float4 NIA = make_float4(gn[1+o], gn[2+o], gn[3+o], gn[4+o]);
    const float4 NIB = make_float4(gn[5+o], gn[6+o], gn[7+o], gn[8+o]);
    const float RT  = (p == 0) ? gr[0] : 0.0f;
    const float ZT  = (p == 0) ? gz[0] : 0.0f;
    const float NTW = (p == 0) ? gn[0] : 0.0f;
    const float gbr_ = gb[u], gbz_ = gb[64 + u], gbn_ = gb[128 + u];
    const float bnv  = gbn[u];

    if (tid < 64) hbuf[0][tid] = 0.0f;
    __syncthreads();

    // ---------------- GRU scan: 1 barrier/step, quad-DPP reductions ------------
    float hreg = 0.0f;
    float4 xA = *(const float4*)(&xb[0] + o);
    float4 xB = *(const float4*)(&xb[0] + o + 4);
    float tsv = xb[32];
    for (int s = 0; s < NT; ++s) {
        // prefetch next step's x (row NT is the pad row; loaded but never used)
        const float* xrown = &xb[(s + 1) * XB];
        const float4 nxA = *(const float4*)(xrown + o);
        const float4 nxB = *(const float4*)(xrown + o + 4);
        const float ntsv = xrown[32];

        const float4* hv = (const float4*)&hbuf[s & 1][p * 16];
        const float4 h0 = hv[0], h1 = hv[1], h2 = hv[2], h3 = hv[3];

        float ar = dot4(WR0,h0) + dot4(WR1,h1) + dot4(WR2,h2) + dot4(WR3,h3)
                 + dot4(RIA,xA) + dot4(RIB,xB) + RT * tsv;
        float az = dot4(WZ0,h0) + dot4(WZ1,h1) + dot4(WZ2,h2) + dot4(WZ3,h3)
                 + dot4(ZIA,xA) + dot4(ZIB,xB) + ZT * tsv;
        float ahn = dot4(WN0,h0) + dot4(WN1,h1) + dot4(WN2,h2) + dot4(WN3,h3);
        float ain = dot4(NIA,xA) + dot4(NIB,xB) + NTW * tsv;

        ar  = quad_reduce(ar);
        az  = quad_reduce(az);
        ahn = quad_reduce(ahn);
        ain = quad_reduce(ain);

        const float rg = fsigm(ar + gbr_);
        const float zg = fsigm(az + gbz_);
        const float ng = ftanh(ain + gbn_ + rg * (ahn + bnv));
        hreg = ng + zg * (hreg - ng);
        if (p == 0) hbuf[(s + 1) & 1][u] = hreg;
        xA = nxA; xB = nxB; tsv = ntsv;
        __syncthreads();
    }
    // final h in hbuf[0] (NT even)

    // ---------------- context -> latent -> y0 (one-time) ----------------------
    if (tid < 64) {
        const float4* wp = (const float4*)(hlw + tid * 64);
        const float4* hv = (const float4*)&hbuf[0][0];
        float a0 = hlb[tid], a1 = 0.0f;
#pragma unroll
        for (int q = 0; q < 16; q += 2) { a0 += dot4(wp[q], hv[q]); a1 += dot4(wp[q+1], hv[q+1]); }
        tmpb[tid] = a0 + a1;
    }
    __syncthreads();
    float klpart = 0.0f;
    if (tid < 32) {
        const float mean   = tmpb[tid];
        const float logstd = tmpb[32 + tid];
        const float stdv   = __expf(logstd);
        latb[tid] = mean + eps[b * NL + tid] * stdv;
        klpart = 0.5f * (mean * mean + stdv * stdv - 2.0f * logstd - 1.0f);
    }
    __syncthreads();
    if (tid < 64) {
        const float4* wp = (const float4*)(lw0 + tid * 32);
        const float4* lv = (const float4*)latb;
        float a0 = lb0[tid], a1 = 0.0f;
#pragma unroll
        for (int q = 0; q < 8; q += 2) { a0 += dot4(wp[q], lv[q]); a1 += dot4(wp[q+1], lv[q+1]); }
        a0b[tid] = fmaxf(a0 + a1, 0.0f);
    }
    __syncthreads();
    if (tid < 64) {
        const float4* wp = (const float4*)(lw1 + tid * 64);
        const float4* av = (const float4*)a0b;
        float a0 = lb1[tid], a1 = 0.0f;
#pragma unroll
        for (int q = 0; q < 16; q += 2) { a0 += dot4(wp[q], av[q]); a1 += dot4(wp[q+1], av[q+1]); }
        a1b[tid] = fmaxf(a0 + a1, 0.0f);
    }
    __syncthreads();
    if (tid < 64) {
        const float4* wp = (const float4*)(lw2 + tid * 64);
        const float4* tv = (const float4*)a1b;
        float a0 = lb2[tid], a1 = 0.0f;
#pragma unroll
        for (int q = 0; q < 16; q += 2) { a0 += dot4(wp[q], tv[q]); a1 += dot4(wp[q+1], tv[q+1]); }
        ybuf[tid] = a0 + a1;   // y0
    }
    __syncthreads();

    // ---------------- Euler weights -------------------------------------------
    // layers: er = tid>>2 row, ep = tid&3 k-split (16 floats each).
    // hd: hr = tid>>3 row, hp = ((tid&3)<<1)|((tid>>2)&1) -> hd's 8-float slice
    //     [hp*8, hp*8+8) is a SUBSET of the lane's y-slice [ep*16, ep*16+16)
    //     (hp>>1 == ep), so P2's hd reuses P1's y registers: zero extra ds_read.
    const int er = tid >> 2, ep = tid & 3;
    const int hb2 = (tid >> 2) & 1;                  // which half of y-slice
    const int hp = (ep << 1) | hb2;
    const int hr = tid >> 3;
    const float4* q0 = (const float4*)(fw0 + er * 64 + ep * 16);
    const float4 E00=q0[0], E01=q0[1], E02=q0[2], E03=q0[3];
    const float4* q1 = (const float4*)(fw1 + er * 64 + ep * 16);
    const float4 E10=q1[0], E11=q1[1], E12=q1[2], E13=q1[3];
    const float4* q2 = (const float4*)(fw2 + er * 64 + ep * 16);
    const float4 E20=q2[0], E21=q2[1], E22=q2[2], E23=q2[3];
    const float b0 = fb0[er], b1 = fb1[er], b2 = fb2[er];
    const float4* qh = (const float4*)(hdw + hr * 64 + hp * 8);
    const float4 HD0 = qh[0], HD1 = qh[1];
    const float hdbias = hdb[hr];
    const float dts = DT0 * scale_p[0];
    float ylocal = (ep == 0) ? ybuf[er] : 0.0f;   // y[er] owned by lane (er,0)
    float rec = 0.0f;

    // ---------------- Euler scan: 3 phases, DPP reductions --------------------
    for (int s = 0; s < NT; ++s) {
        // P1: layer0 from y_s (keep y-slice regs alive for P2's hd)
        const float4* yv = (const float4*)ybuf;
        const float4 ya0 = yv[ep*4+0], ya1 = yv[ep*4+1],
                     ya2 = yv[ep*4+2], ya3 = yv[ep*4+3];
        {
            float l0 = dot4(E00, ya0) + dot4(E01, ya1)
                     + dot4(E02, ya2) + dot4(E03, ya3);
            l0 = quad_reduce(l0);
            if (ep == 0) a0b[er] = fsoftplus(l0 + b0);
        }
        __syncthreads();
        // P2: layer1 from a0 | hd projection of y_s from retained regs + recon
        {
            const float4* av = (const float4*)a0b;
            float l1 = dot4(E10, av[ep*4+0]) + dot4(E11, av[ep*4+1])
                     + dot4(E12, av[ep*4+2]) + dot4(E13, av[ep*4+3]);
            l1 = quad_reduce(l1);

            // hd slice = half of the y-slice already in registers
            const float4 za = hb2 ? ya2 : ya0;
            const float4 zb = hb2 ? ya3 : ya1;
            float ph = dot4(HD0, za) + dot4(HD1, zb);
            ph = red8(ph);
            if (ep == 0) a1b[er] = fsoftplus(l1 + b1);
            if ((tid & 7) == 0 && s > 0) {
                const float d = xb[(s - 1) * XB + hr] - (ph + hdbias);
                rec += d * d;
            }
        }
        __syncthreads();
        // P3: layer2 + y update (lane (er,0) keeps y in register)
        {
            const float4* bv = (const float4*)a1b;
            float l2 = dot4(E20, bv[ep*4+0]) + dot4(E21, bv[ep*4+1])
                     + dot4(E22, bv[ep*4+2]) + dot4(E23, bv[ep*4+3]);
            l2 = quad_reduce(l2);
            if (ep == 0) {
                ylocal += dts * ftanh(l2 + b2);
                ybuf[er] = ylocal;
            }
        }
        __syncthreads();
    }

    // epilogue: hd of y_T vs ys[T-1]
    {
        const float4* yv = (const float4*)ybuf;
        const float4 za = yv[hp*2+0], zb = yv[hp*2+1];
        float ph = dot4(HD0, za) + dot4(HD1, zb);
        ph = red8(ph);
        if ((tid & 7) == 0) {
            const float d = xb[(NT - 1) * XB + hr] - (ph + hdbias);
            rec += d * d;
            redr[hr] = rec;
        }
    }
    // KL reduce (lanes 0..31 of wave 0)
    float klv = klpart;
    klv += __shfl_xor(klv, 1);
    klv += __shfl_xor(klv, 2);
    klv += __shfl_xor(klv, 4);
    klv += __shfl_xor(klv, 8);
    klv += __shfl_xor(klv, 16);
    __syncthreads();
    if (tid == 0) {
        float rs = 0.0f;
#pragma unroll
        for (int k2 = 0; k2 < 32; ++k2) rs += redr[k2];
        out[b] = 0.5f * rs + klv;
    }
}

extern "C" void kernel_launch(void* const* d_in, const int* in_sizes, int n_in,
                              void* d_out, int out_size, void* d_ws, size_t ws_size,
                              hipStream_t stream) {
    (void)in_sizes; (void)n_in; (void)out_size; (void)d_ws; (void)ws_size;
    const float* ts      = (const float*)d_in[0];
    const float* ys      = (const float*)d_in[1];
    const float* eps     = (const float*)d_in[2];
    const float* scale_p = (const float*)d_in[3];
    const float* fw0     = (const float*)d_in[4];
    const float* fb0     = (const float*)d_in[5];
    const float* fw1     = (const float*)d_in[6];
    const float* fb1     = (const float*)d_in[7];
    const float* fw2     = (const float*)d_in[8];
    const float* fb2     = (const float*)d_in[9];
    const float* gwi     = (const float*)d_in[10];
    const float* gwh     = (const float*)d_in[11];
    const float* gbv     = (const float*)d_in[12];
    const float* gbn     = (const float*)d_in[13];
    const float* hlw     = (const float*)d_in[14];
    const float* hlb     = (const float*)d_in[15];
    const float* lw0     = (const float*)d_in[16];
    const float* lb0     = (const float*)d_in[17];
    const float* lw1     = (const float*)d_in[18];
    const float* lb1     = (const float*)d_in[19];
    const float* lw2     = (const float*)d_in[20];
    const float* lb2     = (const float*)d_in[21];
    const float* hdw     = (const float*)d_in[22];
    const float* hdb     = (const float*)d_in[23];
    float* out = (float*)d_out;

    hipLaunchKernelGGL(latentode_fused, dim3(NB), dim3(256), 0, stream,
                       ts, ys, eps, scale_p, fw0, fb0, fw1, fb1, fw2, fb2,
                       gwi, gwh, gbv, gbn, hlw, hlb, lw0, lb0, lw1, lb1,
                       lw2, lb2, hdw, hdb, out);
}

// Round 9
// 1068.779 us; speedup vs baseline: 1.1202x; 1.0450x over previous
//
#include <hip/hip_runtime.h>
#include <math.h>

#define NB 256
#define NT 1024
#define ND 32
#define NH 64
#define NL 32
#define DT0 0.4f
#define XB 36   // staged x row: [y0..y31, ts, pad3]

__device__ __forceinline__ float dot4(float4 a, float4 b) {
    return a.x * b.x + a.y * b.y + a.z * b.z + a.w * b.w;
}
__device__ __forceinline__ float fsigm(float x) {
    return __fdividef(1.0f, 1.0f + __expf(-x));
}
__device__ __forceinline__ float ftanh(float x) {
    float cx = fminf(fmaxf(x, -15.0f), 15.0f);
    float e2 = __expf(2.0f * cx);
    return __fdividef(e2 - 1.0f, e2 + 1.0f);
}
__device__ __forceinline__ float fsoftplus(float x) {
    return fmaxf(x, 0.0f) + __logf(1.0f + __expf(-fabsf(x)));
}

// DPP cross-lane adds on the VALU pipe (no LDS/bpermute latency).
// 0xB1 = quad_perm xor1 ; 0x4E = quad_perm xor2 ; 0x104 = row_shl:4
// (lane i <- lane i+4, 0-filled at row edge with bound_ctrl): completes an
// 8-lane group sum at lanes with (lane&7)==0.
template <int CTRL>
__device__ __forceinline__ float dpp_add(float x) {
    int t = __builtin_amdgcn_update_dpp(0, __float_as_int(x), CTRL, 0xF, 0xF, true);
    return x + __int_as_float(t);
}
__device__ __forceinline__ float quad_reduce(float x) {
    x = dpp_add<0xB1>(x);
    x = dpp_add<0x4E>(x);
    return x;
}
__device__ __forceinline__ float red8(float x) {   // total valid at (lane&7)==0
    x = dpp_add<0xB1>(x);
    x = dpp_add<0x4E>(x);
    x = dpp_add<0x104>(x);
    return x;
}

extern "C" __global__ void __launch_bounds__(256, 1)
latentode_fused(const float* __restrict__ ts,      // (B,T)
                const float* __restrict__ ys,      // (B,T,D)
                const float* __restrict__ eps,     // (B,L)
                const float* __restrict__ scale_p, // ()
                const float* __restrict__ fw0, const float* __restrict__ fb0,
                const float* __restrict__ fw1, const float* __restrict__ fb1,
                const float* __restrict__ fw2, const float* __restrict__ fb2,
                const float* __restrict__ gwi, const float* __restrict__ gwh,
                const float* __restrict__ gb,  const float* __restrict__ gbn,
                const float* __restrict__ hlw, const float* __restrict__ hlb,
                const float* __restrict__ lw0, const float* __restrict__ lb0,
                const float* __restrict__ lw1, const float* __restrict__ lb1,
                const float* __restrict__ lw2, const float* __restrict__ lb2,
                const float* __restrict__ hdw, const float* __restrict__ hdb,
                float* __restrict__ out)
{
    const int b   = blockIdx.x;
    const int tid = threadIdx.x;

    __shared__ __align__(16) float xb[(NT + 2) * XB];  // +2 pad rows: clampless unrolled prefetch
    __shared__ __align__(16) float hbuf[2][64];        // GRU h, double-buffered (static idx via unroll)
    __shared__ __align__(16) float a0b[64];
    __shared__ __align__(16) float a1b[64];
    __shared__ __align__(16) float tmpb[64];
    __shared__ __align__(16) float ybuf[64];
    __shared__ __align__(16) float latb[32];
    __shared__ float redr[32];

    // ---------------- stage ts/ys into LDS (one-time) -------------------------
    for (int i = tid; i < NT * 8; i += 256) {
        const int row = i >> 3, q = i & 7;
        *(float4*)&xb[row * XB + q * 4] =
            *(const float4*)(ys + (size_t)(b * NT + row) * ND + q * 4);
    }
    for (int i = tid; i < NT; i += 256) xb[i * XB + 32] = ts[b * NT + i];

    // ---------------- GRU weights: unit u = tid>>2, k-part p = tid&3 ----------
    const int u = tid >> 2;
    const int p = tid & 3;
    const float4* whr = (const float4*)(gwh + (u)       * 64 + p * 16);
    const float4* whz = (const float4*)(gwh + (64 + u)  * 64 + p * 16);
    const float4* whn = (const float4*)(gwh + (128 + u) * 64 + p * 16);
    const float4 WR0=whr[0], WR1=whr[1], WR2=whr[2], WR3=whr[3];
    const float4 WZ0=whz[0], WZ1=whz[1], WZ2=whz[2], WZ3=whz[3];
    const float4 WN0=whn[0], WN1=whn[1], WN2=whn[2], WN3=whn[3];
    const float* gr = gwi + u * 33;
    const float* gz = gwi + (64 + u) * 33;
    const float* gn = gwi + (128 + u) * 33;
    const int o = 8 * p;
    const float4 RIA = make_float4(gr[1+o], gr[2+o], gr[3+o], gr[4+o]);
    const float4 RIB = make_float4(gr[5+o], gr[6+o], gr[7+o], gr[8+o]);
    const float4 ZIA = make_float4(gz[1+o], gz[2+o], gz[3+o], gz[4+o]);
    const float4 ZIB = make_float4(gz[5+o], gz[6+o], gz[7+o], gz[8+o]);
    const float4 NIA = make_float4(gn[1+o], gn[2+o], gn[3+o], gn[4+o]);
    const float4 NIB = make_float4(gn[5+o], gn[6+o], gn[7+o], gn[8+o]);
    const float RT  = (p == 0) ? gr[0] : 0.0f;
    const float ZT  = (p == 0) ? gz[0] : 0.0f;
    const float NTW = (p == 0) ? gn[0] : 0.0f;
    const float gbr_ = gb[u], gbz_ = gb[64 + u], gbn_ = gb[128 + u];
    const float bnv  = gbn[u];

    if (tid < 64) hbuf[0][tid] = 0.0f;
    __syncthreads();

    // ---------------- GRU scan: unroll x2, 1 barrier/step, DPP reductions -----
    float hreg = 0.0f;
    float4 xA = *(const float4*)(&xb[0] + o);
    float4 xB = *(const float4*)(&xb[0] + o + 4);
    float tsv = xb[32];

#define GRU_STEP(SROW, RD, WR)                                                  \
    {                                                                           \
        const float* xrown = &xb[((SROW) + 1) * XB];                            \
        const float4 nxA = *(const float4*)(xrown + o);                         \
        const float4 nxB = *(const float4*)(xrown + o + 4);                     \
        const float ntsv = xrown[32];                                           \
        const float4* hv = (const float4*)&hbuf[RD][p * 16];                    \
        const float4 h0 = hv[0], h1 = hv[1], h2 = hv[2], h3 = hv[3];            \
        float ar = dot4(WR0,h0) + dot4(WR1,h1) + dot4(WR2,h2) + dot4(WR3,h3)    \
                 + dot4(RIA,xA) + dot4(RIB,xB) + RT * tsv;                      \
        float az = dot4(WZ0,h0) + dot4(WZ1,h1) + dot4(WZ2,h2) + dot4(WZ3,h3)    \
                 + dot4(ZIA,xA) + dot4(ZIB,xB) + ZT * tsv;                      \
        float ahn = dot4(WN0,h0) + dot4(WN1,h1) + dot4(WN2,h2) + dot4(WN3,h3);  \
        float ain = dot4(NIA,xA) + dot4(NIB,xB) + NTW * tsv;                    \
        ar  = quad_reduce(ar);                                                  \
        az  = quad_reduce(az);                                                  \
        ahn = quad_reduce(ahn);                                                 \
        ain = quad_reduce(ain);                                                 \
        const float rg = fsigm(ar + gbr_);                                      \
        const float zg = fsigm(az + gbz_);                                      \
        const float ng = ftanh(ain + gbn_ + rg * (ahn + bnv));                  \
        hreg = ng + zg * (hreg - ng);                                           \
        if (p == 0) hbuf[WR][u] = hreg;                                         \
        xA = nxA; xB = nxB; tsv = ntsv;                                         \
        __syncthreads();                                                        \
    }

    for (int s = 0; s < NT; s += 2) {
        GRU_STEP(s,     0, 1);
        GRU_STEP(s + 1, 1, 0);
    }
    // final h in hbuf[0] (NT even)

    // ---------------- context -> latent -> y0 (one-time) ----------------------
    if (tid < 64) {
        const float4* wp = (const float4*)(hlw + tid * 64);
        const float4* hv = (const float4*)&hbuf[0][0];
        float a0 = hlb[tid], a1 = 0.0f;
#pragma unroll
        for (int q = 0; q < 16; q += 2) { a0 += dot4(wp[q], hv[q]); a1 += dot4(wp[q+1], hv[q+1]); }
        tmpb[tid] = a0 + a1;
    }
    __syncthreads();
    float klpart = 0.0f;
    if (tid < 32) {
        const float mean   = tmpb[tid];
        const float logstd = tmpb[32 + tid];
        const float stdv   = __expf(logstd);
        latb[tid] = mean + eps[b * NL + tid] * stdv;
        klpart = 0.5f * (mean * mean + stdv * stdv - 2.0f * logstd - 1.0f);
    }
    __syncthreads();
    if (tid < 64) {
        const float4* wp = (const float4*)(lw0 + tid * 32);
        const float4* lv = (const float4*)latb;
        float a0 = lb0[tid], a1 = 0.0f;
#pragma unroll
        for (int q = 0; q < 8; q += 2) { a0 += dot4(wp[q], lv[q]); a1 += dot4(wp[q+1], lv[q+1]); }
        a0b[tid] = fmaxf(a0 + a1, 0.0f);
    }
    __syncthreads();
    if (tid < 64) {
        const float4* wp = (const float4*)(lw1 + tid * 64);
        const float4* av = (const float4*)a0b;
        float a0 = lb1[tid], a1 = 0.0f;
#pragma unroll
        for (int q = 0; q < 16; q += 2) { a0 += dot4(wp[q], av[q]); a1 += dot4(wp[q+1], av[q+1]); }
        a1b[tid] = fmaxf(a0 + a1, 0.0f);
    }
    __syncthreads();
    if (tid < 64) {
        const float4* wp = (const float4*)(lw2 + tid * 64);
        const float4* tv = (const float4*)a1b;
        float a0 = lb2[tid], a1 = 0.0f;
#pragma unroll
        for (int q = 0; q < 16; q += 2) { a0 += dot4(wp[q], tv[q]); a1 += dot4(wp[q+1], tv[q+1]); }
        ybuf[tid] = a0 + a1;   // y0
    }
    __syncthreads();

    // ---------------- Euler weights -------------------------------------------
    // layers: er = tid>>2 row, ep = tid&3 k-split (16 floats each).
    // hd: hr = tid>>3 row, hp = ((tid&3)<<1)|((tid>>2)&1) -> hd's 8-float slice
    //     is a SUBSET of the lane's y-slice, so hd reuses P1's y registers.
    const int er = tid >> 2, ep = tid & 3;
    const int hb2 = (tid >> 2) & 1;
    const int hp = (ep << 1) | hb2;
    const int hr = tid >> 3;
    const float4* q0 = (const float4*)(fw0 + er * 64 + ep * 16);
    const float4 E00=q0[0], E01=q0[1], E02=q0[2], E03=q0[3];
    const float4* q1 = (const float4*)(fw1 + er * 64 + ep * 16);
    const float4 E10=q1[0], E11=q1[1], E12=q1[2], E13=q1[3];
    const float4* q2 = (const float4*)(fw2 + er * 64 + ep * 16);
    const float4 E20=q2[0], E21=q2[1], E22=q2[2], E23=q2[3];
    const float b0 = fb0[er], b1 = fb1[er], b2 = fb2[er];
    const float4* qh = (const float4*)(hdw + hr * 64 + hp * 8);
    const float4 HD0 = qh[0], HD1 = qh[1];
    const float hdbias = hdb[hr];
    const float dts = DT0 * scale_p[0];
    float ylocal = (ep == 0) ? ybuf[er] : 0.0f;   // y[er] owned by lane (er,0)
    float rec = 0.0f;

#define EULER_STEP(SS, DO_REC)                                                  \
    {                                                                           \
        const float4* yv = (const float4*)ybuf;                                 \
        const float4 ya0 = yv[ep*4+0], ya1 = yv[ep*4+1],                        \
                     ya2 = yv[ep*4+2], ya3 = yv[ep*4+3];                        \
        {                                                                       \
            float l0 = dot4(E00, ya0) + dot4(E01, ya1)                          \
                     + dot4(E02, ya2) + dot4(E03, ya3);                         \
            l0 = quad_reduce(l0);                                               \
            if (ep == 0) a0b[er] = fsoftplus(l0 + b0);                          \
        }                                                                       \
        __syncthreads();                                                        \
        {                                                                       \
            const float4* av = (const float4*)a0b;                              \
            float l1 = dot4(E10, av[ep*4+0]) + dot4(E11, av[ep*4+1])            \
                     + dot4(E12, av[ep*4+2]) + dot4(E13, av[ep*4+3]);           \
            l1 = quad_reduce(l1);                                               \
            const float4 za = hb2 ? ya2 : ya0;                                  \
            const float4 zb = hb2 ? ya3 : ya1;                                  \
            float ph = dot4(HD0, za) + dot4(HD1, zb);                           \
            ph = red8(ph);                                                      \
            if (ep == 0) a1b[er] = fsoftplus(l1 + b1);                          \
            if (DO_REC && (tid & 7) == 0) {                                     \
                const float d = xb[((SS) - 1) * XB + hr] - (ph + hdbias);       \
                rec += d * d;                                                   \
            }                                                                   \
        }                                                                       \
        __syncthreads();                                                        \
        {                                                                       \
            const float4* bv = (const float4*)a1b;                              \
            float l2 = dot4(E20, bv[ep*4+0]) + dot4(E21, bv[ep*4+1])            \
                     + dot4(E22, bv[ep*4+2]) + dot4(E23, bv[ep*4+3]);           \
            l2 = quad_reduce(l2);                                               \
            if (ep == 0) {                                                      \
                ylocal += dts * ftanh(l2 + b2);                                 \
                ybuf[er] = ylocal;                                              \
            }                                                                   \
        }                                                                       \
        __syncthreads();                                                        \
    }

    // peeled first step (no recon term)
    EULER_STEP(0, false);
    for (int s = 1; s < NT - 1; s += 2) {
        EULER_STEP(s,     true);
        EULER_STEP(s + 1, true);
    }
    EULER_STEP(NT - 1, true);

    // epilogue: hd of y_T vs ys[T-1]
    {
        const float4* yv = (const float4*)ybuf;
        const float4 za = yv[hp*2+0], zb = yv[hp*2+1];
        float ph = dot4(HD0, za) + dot4(HD1, zb);
        ph = red8(ph);
        if ((tid & 7) == 0) {
            const float d = xb[(NT - 1) * XB + hr] - (ph + hdbias);
            rec += d * d;
            redr[hr] = rec;
        }
    }
    // KL reduce (lanes 0..31 of wave 0)
    float klv = klpart;
    klv += __shfl_xor(klv, 1);
    klv += __shfl_xor(klv, 2);
    klv += __shfl_xor(klv, 4);
    klv += __shfl_xor(klv, 8);
    klv += __shfl_xor(klv, 16);
    __syncthreads();
    if (tid == 0) {
        float rs = 0.0f;
#pragma unroll
        for (int k2 = 0; k2 < 32; ++k2) rs += redr[k2];
        out[b] = 0.5f * rs + klv;
    }
}

extern "C" void kernel_launch(void* const* d_in, const int* in_sizes, int n_in,
                              void* d_out, int out_size, void* d_ws, size_t ws_size,
                              hipStream_t stream) {
    (void)in_sizes; (void)n_in; (void)out_size; (void)d_ws; (void)ws_size;
    const float* ts      = (const float*)d_in[0];
    const float* ys      = (const float*)d_in[1];
    const float* eps     = (const float*)d_in[2];
    const float* scale_p = (const float*)d_in[3];
    const float* fw0     = (const float*)d_in[4];
    const float* fb0     = (const float*)d_in[5];
    const float* fw1     = (const float*)d_in[6];
    const float* fb1     = (const float*)d_in[7];
    const float* fw2     = (const float*)d_in[8];
    const float* fb2     = (const float*)d_in[9];
    const float* gwi     = (const float*)d_in[10];
    const float* gwh     = (const float*)d_in[11];
    const float* gbv     = (const float*)d_in[12];
    const float* gbn     = (const float*)d_in[13];
    const float* hlw     = (const float*)d_in[14];
    const float* hlb     = (const float*)d_in[15];
    const float* lw0     = (const float*)d_in[16];
    const float* lb0     = (const float*)d_in[17];
    const float* lw1     = (const float*)d_in[18];
    const float* lb1     = (const float*)d_in[19];
    const float* lw2     = (const float*)d_in[20];
    const float* lb2     = (const float*)d_in[21];
    const float* hdw     = (const float*)d_in[22];
    const float* hdb     = (const float*)d_in[23];
    float* out = (float*)d_out;

    hipLaunchKernelGGL(latentode_fused, dim3(NB), dim3(256), 0, stream,
                       ts, ys, eps, scale_p, fw0, fb0, fw1, fb1, fw2, fb2,
                       gwi, gwh, gbv, gbn, hlw, hlb, lw0, lb0, lw1, lb1,
                       lw2, lb2, hdw, hdb, out);
}